// Round 5
// baseline (174.987 us; speedup 1.0000x reference)
//
#include <hip/hip_runtime.h>
#include <math.h>

// DbrxRouter on MI355X:
//   logits = x[8192,6144] @ W^T[6144,16]; softmax; top-4; p=1 renorm.
//   Renorm cancels the softmax denominator -> only top-4 logits needed.
//
// R4 lesson: per-wave W re-reads (805 MB through L1/L2) were the cost, not
// occupancy. This version stages W in LDS (double-buffered 2x32KB chunks),
// amortized over 16 tokens/block; each wave covers FULL H for its 4 tokens
// (no cross-wave reduction). x prefetched one chunk ahead in registers,
// W staged one chunk ahead reg->LDS (T14 issue-early/write-late).

constexpr int H       = 6144;
constexpr int E       = 16;
constexpr int HC      = 512;          // H chunk staged in LDS (16 x 512 fp32 = 32KB)
constexpr int NCH     = H / HC;       // 12
constexpr int TPB     = 256;          // 4 waves
constexpr int TOK_PB  = 16;           // 4 tokens per wave
constexpr int T_TOTAL = 8192;

__global__ __launch_bounds__(TPB, 2)
void dbrx_router(const float* __restrict__ x,
                 const float* __restrict__ w,
                 float* __restrict__ out)
{
    __shared__ float wlds[2][E * HC];   // 2 x 32KB W chunk double-buffer
    __shared__ float lred[4][64];       // [wave][t_loc*16+e] final logits

    const int tid  = threadIdx.x;
    const int wave = tid >> 6;
    const int lane = tid & 63;
    const int tok0 = blockIdx.x * TOK_PB + wave * 4;   // this wave's 4 tokens

    // W staging: thread t, round j loads W[2j + (t>>7)][c*HC + (t&127)*4]
    //   -> LDS float idx j*1024 + t*4 (contiguous 4KB per round, 16B/lane).
    const float* wstage = w + (size_t)(tid >> 7) * H + (tid & 127) * 4;
    const float* xbase  = x + (size_t)tok0 * H + lane * 4;

    float acc[64];                       // [t*16+e], all indices static
    #pragma unroll
    for (int i = 0; i < 64; ++i) acc[i] = 0.f;

    float4 wst[8];                       // W chunk c+1 in regs
    float4 xa[8], xb[8];                 // x ping-pong: [t*2+sub]

    // ---- prologue: W chunk0 -> LDS buf0; W chunk1 -> regs; x chunk0 -> xa
    #pragma unroll
    for (int j = 0; j < 8; ++j)
        wst[j] = *reinterpret_cast<const float4*>(wstage + (size_t)(2 * j) * H);
    #pragma unroll
    for (int j = 0; j < 8; ++j)
        *reinterpret_cast<float4*>(&wlds[0][j * 1024 + tid * 4]) = wst[j];
    #pragma unroll
    for (int t = 0; t < 4; ++t)
        #pragma unroll
        for (int s = 0; s < 2; ++s)
            xa[t * 2 + s] = *reinterpret_cast<const float4*>(
                xbase + (size_t)t * H + s * 256);
    __syncthreads();                     // buf0 published
    #pragma unroll
    for (int j = 0; j < 8; ++j)
        wst[j] = *reinterpret_cast<const float4*>(wstage + (size_t)(2 * j) * H + HC);

    // ---- main loop. B = buffer parity (literal), XC = current x, XN = next x.
    // Barrier at END of each step publishes buf[1-B] (written at top) and
    // retires all reads of buf[B] before it's overwritten two steps later.
#define STEP(C, B, XC, XN) do {                                                \
        if ((C) < NCH - 1) {             /* write chunk C+1 into buf 1-B */    \
            _Pragma("unroll")                                                  \
            for (int j = 0; j < 8; ++j)                                        \
                *reinterpret_cast<float4*>(                                    \
                    &wlds[1 - (B)][j * 1024 + tid * 4]) = wst[j];              \
        }                                                                      \
        if ((C) < NCH - 2) {             /* issue W loads for chunk C+2 */     \
            _Pragma("unroll")                                                  \
            for (int j = 0; j < 8; ++j)                                        \
                wst[j] = *reinterpret_cast<const float4*>(                     \
                    wstage + (size_t)(2 * j) * H + ((C) + 2) * HC);            \
        }                                                                      \
        if ((C) < NCH - 1) {             /* prefetch x chunk C+1 */            \
            _Pragma("unroll")                                                  \
            for (int t = 0; t < 4; ++t)                                        \
                _Pragma("unroll")                                              \
                for (int s = 0; s < 2; ++s)                                    \
                    XN[t * 2 + s] = *reinterpret_cast<const float4*>(          \
                        xbase + (size_t)t * H + ((C) + 1) * HC + s * 256);     \
        }                                                                      \
        _Pragma("unroll")                                                      \
        for (int s = 0; s < 2; ++s) {    /* compute chunk C from buf B */      \
            _Pragma("unroll")                                                  \
            for (int eb = 0; eb < 4; ++eb) {                                   \
                float4 wv[4];                                                  \
                _Pragma("unroll")                                              \
                for (int e = 0; e < 4; ++e)                                    \
                    wv[e] = *reinterpret_cast<const float4*>(                  \
                        &wlds[B][(eb * 4 + e) * HC + s * 256 + lane * 4]);     \
                _Pragma("unroll")                                              \
                for (int t = 0; t < 4; ++t)                                    \
                    _Pragma("unroll")                                          \
                    for (int e = 0; e < 4; ++e) {                              \
                        float sm = acc[t * 16 + eb * 4 + e];                   \
                        sm = fmaf(XC[t * 2 + s].x, wv[e].x, sm);               \
                        sm = fmaf(XC[t * 2 + s].y, wv[e].y, sm);               \
                        sm = fmaf(XC[t * 2 + s].z, wv[e].z, sm);               \
                        sm = fmaf(XC[t * 2 + s].w, wv[e].w, sm);               \
                        acc[t * 16 + eb * 4 + e] = sm;                         \
                    }                                                          \
            }                                                                  \
        }                                                                      \
        __syncthreads();                                                       \
    } while (0)

    for (int cc = 0; cc < NCH; cc += 2) {   // 6 iters; parity of buffers static
        STEP(cc,     0, xa, xb);
        STEP(cc + 1, 1, xb, xa);
    }
#undef STEP

    // Butterfly reduce-scatter: 64 partials -> lane l holds fully-reduced
    // acc[l] = logits[token tok0+(l>>4)][expert l&15]. Fully static.
#define RSTEP(S) do {                                                  \
        constexpr int HN = 32 >> (S);                                  \
        const bool hi = (lane & HN) != 0;                              \
        _Pragma("unroll")                                              \
        for (int i = 0; i < HN; ++i) {                                 \
            float send = hi ? acc[i] : acc[i + HN];                    \
            float keep = hi ? acc[i + HN] : acc[i];                    \
            float recv = __shfl_xor(send, HN, 64);                     \
            acc[i] = keep + recv;                                      \
        }                                                              \
    } while (0)
    RSTEP(0); RSTEP(1); RSTEP(2); RSTEP(3); RSTEP(4); RSTEP(5);
#undef RSTEP

    lred[wave][lane] = acc[0];
    __syncthreads();

    // One thread per token: top-4 (strict > == lowest-index tie-break,
    // matching np/jax) + renormalized exp weights. Token = blk*16 + tid.
    if (tid < TOK_PB) {
        float lg[16];
        #pragma unroll
        for (int e = 0; e < 16; ++e)
            lg[e] = lred[tid >> 2][(tid & 3) * 16 + e];

        float topv[4];
        int   topi[4];
        #pragma unroll
        for (int k = 0; k < 4; ++k) {
            float m = lg[0]; int mi = 0;
            #pragma unroll
            for (int e = 1; e < 16; ++e)
                if (lg[e] > m) { m = lg[e]; mi = e; }
            topv[k] = m; topi[k] = mi;
            #pragma unroll
            for (int e = 0; e < 16; ++e)          // static-index mask-out
                if (e == mi) lg[e] = -INFINITY;
        }

        float ex[4]; float sum = 0.f;
        #pragma unroll
        for (int k = 0; k < 4; ++k) { ex[k] = __expf(topv[k] - topv[0]); sum += ex[k]; }
        const float inv = 1.0f / sum;

        const int tok = blockIdx.x * TOK_PB + tid;
        #pragma unroll
        for (int k = 0; k < 4; ++k) {
            out[(size_t)tok * 4 + k] = ex[k] * inv;                          // top_weights
            out[(size_t)T_TOTAL * 4 + (size_t)tok * 4 + k] = (float)topi[k]; // top_experts
        }
    }
}

extern "C" void kernel_launch(void* const* d_in, const int* in_sizes, int n_in,
                              void* d_out, int out_size, void* d_ws, size_t ws_size,
                              hipStream_t stream) {
    const float* x = (const float*)d_in[0];   // hidden_states [4,2048,6144] fp32
    const float* w = (const float*)d_in[1];   // router_weight [16,6144] fp32
    float* out     = (float*)d_out;           // [8192*4 weights][8192*4 expert ids]
    dbrx_router<<<T_TOTAL / TOK_PB, TPB, 0, stream>>>(x, w, out);
}

// Round 6
// 75.414 us; speedup vs baseline: 2.3203x; 2.3203x over previous
//
#include <hip/hip_runtime.h>
#include <math.h>

// DbrxRouter on MI355X:
//   logits = x[8192,6144] @ W^T[6144,16]; softmax; top-4; p=1 renorm.
//   Renorm cancels the softmax denominator -> only top-4 logits needed.
//
// Ledger: R1 57.9us (W/L2 per wave, grid 512); R4 69.8us (grid 2048, W traffic
// x4); R2/R3/R5 spilled (WRITE_SIZE >> output) whenever live regs > ~125.
// This round: W double-buffered in LDS in SMALL chunks (HC=256 floats,
// 16KB/buf), staged with only 16 regs; 16 tokens/block amortize W; live set
// acc64+stg16+xv16+wv16 ~ 124 = R1's proven no-spill budget.

constexpr int H       = 6144;
constexpr int E       = 16;
constexpr int HC      = 256;          // chunk: one float4 per lane per expert
constexpr int NCH     = H / HC;       // 24
constexpr int TPB     = 256;          // 4 waves
constexpr int TOK_PB  = 16;           // 4 tokens per wave, full H per wave
constexpr int T_TOTAL = 8192;

__global__ __launch_bounds__(TPB, 2)
void dbrx_router(const float* __restrict__ x,
                 const float* __restrict__ w,
                 float* __restrict__ out)
{
    __shared__ float wlds[2][E * HC];   // 2 x 16KB W chunk double-buffer
    __shared__ float lred[4][64];       // [wave][t_loc*16+e] final logits

    const int tid  = threadIdx.x;
    const int wave = tid >> 6;
    const int lane = tid & 63;
    const int tok0 = blockIdx.x * TOK_PB + wave * 4;   // this wave's 4 tokens

    // Stage round j (j=0..3): this thread handles expert e=j*4+wave,
    // floats [c*HC + lane*4 .. +4): global and LDS both wave-contiguous 1KB.
    const float* xb = x + (size_t)tok0 * H + lane * 4;

    float acc[64];                       // [t*16+e], all indices static
    #pragma unroll
    for (int i = 0; i < 64; ++i) acc[i] = 0.f;

    float4 stg[4];                       // staging regs for next W chunk

    // ---- prologue: W chunk 0 -> LDS buf 0
    #pragma unroll
    for (int j = 0; j < 4; ++j)
        stg[j] = *reinterpret_cast<const float4*>(
            w + (size_t)(j * 4 + wave) * H + lane * 4);
    #pragma unroll
    for (int j = 0; j < 4; ++j)
        *reinterpret_cast<float4*>(
            &wlds[0][(j * 4 + wave) * HC + lane * 4]) = stg[j];
    __syncthreads();

    // ---- main loop: compute chunk C from buf B while loading C+1 into regs;
    //      barrier; write regs -> buf 1-B; barrier. Two barriers per chunk.
#define PSTEP(C, B) do {                                                       \
        if ((C) + 1 < NCH) {            /* issue W loads for chunk C+1 */      \
            _Pragma("unroll")                                                  \
            for (int j = 0; j < 4; ++j)                                        \
                stg[j] = *reinterpret_cast<const float4*>(                     \
                    w + (size_t)(j * 4 + wave) * H + ((C) + 1) * HC + lane * 4); \
        }                                                                      \
        {                               /* compute chunk C from buf B */       \
            float4 xv[4];                                                      \
            _Pragma("unroll")                                                  \
            for (int t = 0; t < 4; ++t)                                        \
                xv[t] = *reinterpret_cast<const float4*>(                      \
                    xb + (size_t)t * H + (C) * HC);                            \
            _Pragma("unroll")                                                  \
            for (int eb = 0; eb < 4; ++eb) {                                   \
                float4 wv[4];                                                  \
                _Pragma("unroll")                                              \
                for (int e = 0; e < 4; ++e)                                    \
                    wv[e] = *reinterpret_cast<const float4*>(                  \
                        &wlds[B][(eb * 4 + e) * HC + lane * 4]);               \
                _Pragma("unroll")                                              \
                for (int t = 0; t < 4; ++t)                                    \
                    _Pragma("unroll")                                          \
                    for (int e = 0; e < 4; ++e) {                              \
                        float sm = acc[t * 16 + eb * 4 + e];                   \
                        sm = fmaf(xv[t].x, wv[e].x, sm);                       \
                        sm = fmaf(xv[t].y, wv[e].y, sm);                       \
                        sm = fmaf(xv[t].z, wv[e].z, sm);                       \
                        sm = fmaf(xv[t].w, wv[e].w, sm);                       \
                        acc[t * 16 + eb * 4 + e] = sm;                         \
                    }                                                          \
            }                                                                  \
        }                                                                      \
        __syncthreads();                /* all reads of both bufs retired */   \
        if ((C) + 1 < NCH) {            /* publish chunk C+1 into buf 1-B */   \
            _Pragma("unroll")                                                  \
            for (int j = 0; j < 4; ++j)                                        \
                *reinterpret_cast<float4*>(                                    \
                    &wlds[1 - (B)][(j * 4 + wave) * HC + lane * 4]) = stg[j];  \
        }                                                                      \
        __syncthreads();                                                       \
    } while (0)

    for (int cc = 0; cc < NCH; cc += 2) {   // 12 iters; buffer parity static
        PSTEP(cc,     0);
        PSTEP(cc + 1, 1);
    }
#undef PSTEP

    // Butterfly reduce-scatter: 64 partials -> lane l holds fully-reduced
    // acc[l] = logits[tok0+(l>>4)][expert l&15]. Fully static indices.
#define RSTEP(S) do {                                                  \
        constexpr int HN = 32 >> (S);                                  \
        const bool hi = (lane & HN) != 0;                              \
        _Pragma("unroll")                                              \
        for (int i = 0; i < HN; ++i) {                                 \
            float send = hi ? acc[i] : acc[i + HN];                    \
            float keep = hi ? acc[i + HN] : acc[i];                    \
            float recv = __shfl_xor(send, HN, 64);                     \
            acc[i] = keep + recv;                                      \
        }                                                              \
    } while (0)
    RSTEP(0); RSTEP(1); RSTEP(2); RSTEP(3); RSTEP(4); RSTEP(5);
#undef RSTEP

    lred[wave][lane] = acc[0];
    __syncthreads();

    // One thread per token: top-4 (strict > == lowest-index tie-break,
    // matching np/jax) + renormalized exp weights. Token = blk*16 + tid.
    if (tid < TOK_PB) {
        float lg[16];
        #pragma unroll
        for (int e = 0; e < 16; ++e)
            lg[e] = lred[tid >> 2][(tid & 3) * 16 + e];

        float topv[4];
        int   topi[4];
        #pragma unroll
        for (int k = 0; k < 4; ++k) {
            float m = lg[0]; int mi = 0;
            #pragma unroll
            for (int e = 1; e < 16; ++e)
                if (lg[e] > m) { m = lg[e]; mi = e; }
            topv[k] = m; topi[k] = mi;
            #pragma unroll
            for (int e = 0; e < 16; ++e)          // static-index mask-out
                if (e == mi) lg[e] = -INFINITY;
        }

        float ex[4]; float sum = 0.f;
        #pragma unroll
        for (int k = 0; k < 4; ++k) { ex[k] = __expf(topv[k] - topv[0]); sum += ex[k]; }
        const float inv = 1.0f / sum;

        const int tok = blockIdx.x * TOK_PB + tid;
        #pragma unroll
        for (int k = 0; k < 4; ++k) {
            out[(size_t)tok * 4 + k] = ex[k] * inv;                          // top_weights
            out[(size_t)T_TOTAL * 4 + (size_t)tok * 4 + k] = (float)topi[k]; // top_experts
        }
    }
}

extern "C" void kernel_launch(void* const* d_in, const int* in_sizes, int n_in,
                              void* d_out, int out_size, void* d_ws, size_t ws_size,
                              hipStream_t stream) {
    const float* x = (const float*)d_in[0];   // hidden_states [4,2048,6144] fp32
    const float* w = (const float*)d_in[1];   // router_weight [16,6144] fp32
    float* out     = (float*)d_out;           // [8192*4 weights][8192*4 expert ids]
    dbrx_router<<<T_TOTAL / TOK_PB, TPB, 0, stream>>>(x, w, out);
}

// Round 7
// 47.813 us; speedup vs baseline: 3.6598x; 1.5773x over previous
//
#include <hip/hip_runtime.h>
#include <math.h>
#include <stdint.h>

// DbrxRouter on MI355X:
//   logits = x[8192,6144] @ W^T[6144,16]; softmax; top-4; p=1 renorm.
//   Renorm cancels the softmax denominator -> only top-4 logits needed.
//
// Ledger: R1 57.9us (no spill, grid 512, W via L1); R4 69.8us (no spill,
// W traffic 4x); R2/R3/R5/R6 all spilled whenever staging state + macro
// address hoisting pushed live regs past ~125 (canary: WRITE_SIZE >> 256KB).
// R7: W double-buffered in LDS via __builtin_amdgcn_global_load_lds width=16
// (no staging regs, one barrier/chunk), RUNTIME chunk loop (no 24x address
// hoisting), x prefetched one chunk ahead in static-named ping-pong regs.

constexpr int H       = 6144;
constexpr int E       = 16;
constexpr int HC      = 256;          // floats per chunk per expert (16KB/buf)
constexpr int NCH     = H / HC;       // 24 (even)
constexpr int TPB     = 256;          // 4 waves
constexpr int TOK_PB  = 16;           // 4 tokens per wave, full H per wave
constexpr int T_TOTAL = 8192;

__device__ __forceinline__ void gll16(const float* g, float* l) {
    // global -> LDS direct copy, 16B per lane; dest = wave-uniform base,
    // HW adds lane*16. Completion is covered by vmcnt; __syncthreads()
    // drains vmcnt(0) before s_barrier.
    __builtin_amdgcn_global_load_lds(
        (const __attribute__((address_space(1))) uint32_t*)g,
        (__attribute__((address_space(3))) uint32_t*)l,
        16, 0, 0);
}

__global__ __launch_bounds__(TPB, 2)
void dbrx_router(const float* __restrict__ x,
                 const float* __restrict__ w,
                 float* __restrict__ out)
{
    __shared__ float wlds[2][E * HC];   // 2 x 16KB W chunk double-buffer
    __shared__ float lred[4][64];       // [wave][t_loc*16+e] final logits

    const int tid  = threadIdx.x;
    const int wave = tid >> 6;
    const int lane = tid & 63;
    const int tok0 = blockIdx.x * TOK_PB + wave * 4;   // this wave's 4 tokens

    const float* xptr = x + (size_t)tok0 * H + lane * 4;

    float acc[64];                       // [t*16+e], all indices static
    #pragma unroll
    for (int i = 0; i < 64; ++i) acc[i] = 0.f;

    float4 xa[4], xf[4];                 // x ping-pong, static names only

    // ---- prologue: W chunk 0 -> buf0 (gll), x chunk 0 -> xa
    #pragma unroll
    for (int j = 0; j < 4; ++j)
        gll16(w + (size_t)(j * 4 + wave) * H + lane * 4,
              &wlds[0][(j * 4 + wave) * HC]);
    #pragma unroll
    for (int t = 0; t < 4; ++t)
        xa[t] = *reinterpret_cast<const float4*>(xptr + (size_t)t * H);
    __syncthreads();                     // vmcnt drain -> buf0 ready

    // Compute chunk C from wlds[B] with x regs XV (all static indices).
#define COMPUTE(B, XV) do {                                            \
        _Pragma("unroll")                                              \
        for (int eb = 0; eb < 4; ++eb) {                               \
            float4 wv[4];                                              \
            _Pragma("unroll")                                          \
            for (int e = 0; e < 4; ++e)                                \
                wv[e] = *reinterpret_cast<const float4*>(              \
                    &wlds[B][(eb * 4 + e) * HC + lane * 4]);           \
            _Pragma("unroll")                                          \
            for (int t = 0; t < 4; ++t)                                \
                _Pragma("unroll")                                      \
                for (int e = 0; e < 4; ++e) {                          \
                    float s = acc[t * 16 + eb * 4 + e];                \
                    s = fmaf(XV[t].x, wv[e].x, s);                     \
                    s = fmaf(XV[t].y, wv[e].y, s);                     \
                    s = fmaf(XV[t].z, wv[e].z, s);                     \
                    s = fmaf(XV[t].w, wv[e].w, s);                     \
                    acc[t * 16 + eb * 4 + e] = s;                      \
                }                                                      \
        }                                                              \
    } while (0)

    // ---- main loop: runtime loop, 2 steps/iter (static buffer parity).
    // Step A: prefetch chunk c+1 (gll -> buf1, x -> xf), compute c from buf0.
    // Step B: prefetch chunk c+2 (gll -> buf0, x -> xa), compute c+1 from buf1.
    for (int cc = 0; cc < NCH; cc += 2) {
        {   // step A (cc even; cc+1 < NCH always since NCH even)
            #pragma unroll
            for (int j = 0; j < 4; ++j)
                gll16(w + (size_t)(j * 4 + wave) * H + (cc + 1) * HC + lane * 4,
                      &wlds[1][(j * 4 + wave) * HC]);
            #pragma unroll
            for (int t = 0; t < 4; ++t)
                xf[t] = *reinterpret_cast<const float4*>(
                    xptr + (size_t)t * H + (cc + 1) * HC);
            COMPUTE(0, xa);
            __syncthreads();             // buf1 ready; buf0 reads retired
        }
        {   // step B
            if (cc + 2 < NCH) {
                #pragma unroll
                for (int j = 0; j < 4; ++j)
                    gll16(w + (size_t)(j * 4 + wave) * H + (cc + 2) * HC + lane * 4,
                          &wlds[0][(j * 4 + wave) * HC]);
                #pragma unroll
                for (int t = 0; t < 4; ++t)
                    xa[t] = *reinterpret_cast<const float4*>(
                        xptr + (size_t)t * H + (cc + 2) * HC);
            }
            COMPUTE(1, xf);
            __syncthreads();             // buf0 ready; buf1 reads retired
        }
    }
#undef COMPUTE

    // Butterfly reduce-scatter: 64 partials -> lane l holds fully-reduced
    // acc[l] = logits[tok0+(l>>4)][expert l&15]. Fully static indices.
#define RSTEP(S) do {                                                  \
        constexpr int HN = 32 >> (S);                                  \
        const bool hi = (lane & HN) != 0;                              \
        _Pragma("unroll")                                              \
        for (int i = 0; i < HN; ++i) {                                 \
            float send = hi ? acc[i] : acc[i + HN];                    \
            float keep = hi ? acc[i + HN] : acc[i];                    \
            float recv = __shfl_xor(send, HN, 64);                     \
            acc[i] = keep + recv;                                      \
        }                                                              \
    } while (0)
    RSTEP(0); RSTEP(1); RSTEP(2); RSTEP(3); RSTEP(4); RSTEP(5);
#undef RSTEP

    lred[wave][lane] = acc[0];
    __syncthreads();

    // One thread per token: top-4 (strict > == lowest-index tie-break,
    // matching np/jax) + renormalized exp weights. Token = blk*16 + tid.
    if (tid < TOK_PB) {
        float lg[16];
        #pragma unroll
        for (int e = 0; e < 16; ++e)
            lg[e] = lred[tid >> 2][(tid & 3) * 16 + e];

        float topv[4];
        int   topi[4];
        #pragma unroll
        for (int k = 0; k < 4; ++k) {
            float m = lg[0]; int mi = 0;
            #pragma unroll
            for (int e = 1; e < 16; ++e)
                if (lg[e] > m) { m = lg[e]; mi = e; }
            topv[k] = m; topi[k] = mi;
            #pragma unroll
            for (int e = 0; e < 16; ++e)          // static-index mask-out
                if (e == mi) lg[e] = -INFINITY;
        }

        float ex[4]; float sum = 0.f;
        #pragma unroll
        for (int k = 0; k < 4; ++k) { ex[k] = __expf(topv[k] - topv[0]); sum += ex[k]; }
        const float inv = 1.0f / sum;

        const int tok = blockIdx.x * TOK_PB + tid;
        #pragma unroll
        for (int k = 0; k < 4; ++k) {
            out[(size_t)tok * 4 + k] = ex[k] * inv;                          // top_weights
            out[(size_t)T_TOTAL * 4 + (size_t)tok * 4 + k] = (float)topi[k]; // top_experts
        }
    }
}

extern "C" void kernel_launch(void* const* d_in, const int* in_sizes, int n_in,
                              void* d_out, int out_size, void* d_ws, size_t ws_size,
                              hipStream_t stream) {
    const float* x = (const float*)d_in[0];   // hidden_states [4,2048,6144] fp32
    const float* w = (const float*)d_in[1];   // router_weight [16,6144] fp32
    float* out     = (float*)d_out;           // [8192*4 weights][8192*4 expert ids]
    dbrx_router<<<T_TOTAL / TOK_PB, TPB, 0, stream>>>(x, w, out);
}